// Round 4
// baseline (653.702 us; speedup 1.0000x reference)
//
#include <hip/hip_runtime.h>
#include <math.h>

constexpr int PB = 256;          // positions per batch
constexpr int DD = 512;          // model dim
constexpr int NB = 64;           // batch
constexpr int MROWS = NB * PB;   // 16384 rows

typedef __bf16 bf16x8 __attribute__((ext_vector_type(8)));
typedef float f32x4 __attribute__((ext_vector_type(4)));
typedef unsigned short us8 __attribute__((ext_vector_type(8)));

__device__ __forceinline__ unsigned short f2b(float f) {
  unsigned int u = __float_as_uint(f);
  u += 0x7FFFu + ((u >> 16) & 1u);        // round-to-nearest-even
  return (unsigned short)(u >> 16);
}
__device__ __forceinline__ float b2f(unsigned short h) {
  return __uint_as_float(((unsigned int)h) << 16);
}

// direct global->LDS DMA, 16B per lane; lds dest must be wave-uniform base
__device__ __forceinline__ void gload16(const void* g, const void* l) {
  __builtin_amdgcn_global_load_lds(
      (const __attribute__((address_space(1))) unsigned int*)(uintptr_t)g,
      (__attribute__((address_space(3))) unsigned int*)(unsigned int)(uintptr_t)l,
      16, 0, 0);
}

// ---------------------------------------------------------------------------
// MERGED f32 routing GEMM: one dispatch computes BOTH
//   S0 = xp @ wq_r + bq_r   and   S1 = xp @ wk_r + bk_r.
// Body identical to R3's gemm_f32f<1,0,1> (same per-output fmaf chain, k
// ascending) -> outputs BIT-IDENTICAL to the passing R3 run.
// Grid 8x128 = 1024 blocks (4 blocks/CU) + XCD swizzle for A-panel L2 reuse.
// ---------------------------------------------------------------------------
__global__ __launch_bounds__(256) void gemm_routing(
    const float* __restrict__ x,
    const float* __restrict__ wq_r, const float* __restrict__ bq_r,
    const float* __restrict__ wk_r, const float* __restrict__ bk_r,
    float* __restrict__ S0, float* __restrict__ S1)
{
  __shared__ float As[2][16][132];
  __shared__ float Bs[2][16][132];
  const int tid = threadIdx.x;
  const int tx = tid & 15, ty = tid >> 4;

  // bijective XCD swizzle: 1024 blocks, 8 XCDs, 128 per XCD
  const int lid = blockIdx.x + (blockIdx.y << 3);     // gridDim.x == 8
  const int swz = (lid & 7) * 128 + (lid >> 3);
  const int bx = swz & 7, by = swz >> 3;
  const float* Wm   = (bx < 4) ? wq_r : wk_r;
  const float* bias = (bx < 4) ? bq_r : bk_r;
  float* C          = (bx < 4) ? S0 : S1;
  const int row0 = by * 128, col0 = (bx & 3) * 128;

  const int a_r = tid >> 2, a_k4 = (tid & 3) << 2;
  const int g0 = row0 + a_r, g1 = g0 + 64;
  const size_t ag0 = ((size_t)(g0 >> 8) * 257 + (g0 & 255) + 1) * DD + a_k4;
  const size_t ag1 = ((size_t)(g1 >> 8) * 257 + (g1 & 255) + 1) * DD + a_k4;
  const int b_kr = tid >> 5, b_c4 = (tid & 31) << 2;
  const size_t bg0 = (size_t)b_kr * DD + col0 + b_c4;
  const size_t bg1 = bg0 + (size_t)8 * DD;

  float acc[8][8] = {};

  float4 pa0 = *(const float4*)(x + ag0);
  float4 pa1 = *(const float4*)(x + ag1);
  float4 pb0 = *(const float4*)(Wm + bg0);
  float4 pb1 = *(const float4*)(Wm + bg1);

  for (int t = 0; t < 32; ++t) {
    const int buf = t & 1;
    As[buf][a_k4 + 0][a_r] = pa0.x;
    As[buf][a_k4 + 1][a_r] = pa0.y;
    As[buf][a_k4 + 2][a_r] = pa0.z;
    As[buf][a_k4 + 3][a_r] = pa0.w;
    As[buf][a_k4 + 0][a_r + 64] = pa1.x;
    As[buf][a_k4 + 1][a_r + 64] = pa1.y;
    As[buf][a_k4 + 2][a_r + 64] = pa1.z;
    As[buf][a_k4 + 3][a_r + 64] = pa1.w;
    *(float4*)&Bs[buf][b_kr][b_c4] = pb0;
    *(float4*)&Bs[buf][b_kr + 8][b_c4] = pb1;
    __syncthreads();

    if (t < 31) {                       // prefetch next tile under compute
      const int k0 = (t + 1) << 4;
      pa0 = *(const float4*)(x + ag0 + k0);
      pa1 = *(const float4*)(x + ag1 + k0);
      pb0 = *(const float4*)(Wm + bg0 + (size_t)k0 * DD);
      pb1 = *(const float4*)(Wm + bg1 + (size_t)k0 * DD);
    }

#pragma unroll
    for (int kk = 0; kk < 16; ++kk) {
      float4 x0 = *(const float4*)&As[buf][kk][ty * 4];
      float4 x1 = *(const float4*)&As[buf][kk][ty * 4 + 64];
      float4 y0 = *(const float4*)&Bs[buf][kk][tx * 4];
      float4 y1 = *(const float4*)&Bs[buf][kk][tx * 4 + 64];
      float av[8] = {x0.x, x0.y, x0.z, x0.w, x1.x, x1.y, x1.z, x1.w};
      float bv[8] = {y0.x, y0.y, y0.z, y0.w, y1.x, y1.y, y1.z, y1.w};
#pragma unroll
      for (int i = 0; i < 8; ++i)
#pragma unroll
        for (int j = 0; j < 8; ++j)
          acc[i][j] = fmaf(av[i], bv[j], acc[i][j]);
    }
  }

#pragma unroll
  for (int ib = 0; ib < 2; ++ib)
#pragma unroll
    for (int i = 0; i < 4; ++i) {
      const int r = row0 + ib * 64 + ty * 4 + i;
#pragma unroll
      for (int jb = 0; jb < 2; ++jb) {
        const int c = col0 + jb * 64 + tx * 4;
        float4 o;
        o.x = acc[ib * 4 + i][jb * 4 + 0] + bias[c + 0];
        o.y = acc[ib * 4 + i][jb * 4 + 1] + bias[c + 1];
        o.z = acc[ib * 4 + i][jb * 4 + 2] + bias[c + 2];
        o.w = acc[ib * 4 + i][jb * 4 + 3] + bias[c + 3];
        *(float4*)(C + (size_t)r * DD + c) = o;
      }
    }
}

// ---------------------------------------------------------------------------
// Batched scores GEMM (f32, 64x64 tiles, 1024 blocks) — restored from R2
// (known-good ~35 µs; R3's 256-block replacement was occupancy-starved).
// ---------------------------------------------------------------------------
__global__ __launch_bounds__(256) void gemm_scores(
    const float* __restrict__ Q, const float* __restrict__ Kr,
    float* __restrict__ S)
{
  __shared__ float As[16][65];
  __shared__ float Bs[16][65];
  const int b = blockIdx.z;
  const int tid = threadIdx.x;
  const int tx = tid & 15, ty = tid >> 4;
  const int p0 = blockIdx.y * 64, q0 = blockIdx.x * 64;
  const float* Qb = Q + (long)b * PB * DD;
  const float* Kb = Kr + (long)b * PB * DD;
  const int a_r = tid >> 2, a_k = (tid & 3) << 2;
  const int b_n = tid & 63, b_k4 = (tid >> 6) << 2;
  float acc[4][4] = {};

  for (int k0 = 0; k0 < DD; k0 += 16) {
    float4 av = *(const float4*)(Qb + (long)(p0 + a_r) * DD + k0 + a_k);
    As[a_k + 0][a_r] = av.x;
    As[a_k + 1][a_r] = av.y;
    As[a_k + 2][a_r] = av.z;
    As[a_k + 3][a_r] = av.w;
    float4 bv = *(const float4*)(Kb + (long)(q0 + b_n) * DD + k0 + b_k4);
    Bs[b_k4 + 0][b_n] = bv.x;
    Bs[b_k4 + 1][b_n] = bv.y;
    Bs[b_k4 + 2][b_n] = bv.z;
    Bs[b_k4 + 3][b_n] = bv.w;
    __syncthreads();
#pragma unroll
    for (int kk = 0; kk < 16; ++kk) {
      float a[4], b2[4];
#pragma unroll
      for (int i = 0; i < 4; ++i) a[i] = As[kk][ty * 4 + i];
#pragma unroll
      for (int j = 0; j < 4; ++j) b2[j] = Bs[kk][tx * 4 + j];
#pragma unroll
      for (int i = 0; i < 4; ++i)
#pragma unroll
        for (int j = 0; j < 4; ++j)
          acc[i][j] = fmaf(a[i], b2[j], acc[i][j]);
    }
    __syncthreads();
  }

  float* Sb = S + (long)b * PB * PB;
#pragma unroll
  for (int i = 0; i < 4; ++i) {
    int p = p0 + ty * 4 + i;
    int q = q0 + tx * 4;
    float4 o = make_float4(acc[i][0], acc[i][1], acc[i][2], acc[i][3]);
    *(float4*)(Sb + (long)p * PB + q) = o;
  }
}

// ---------------------------------------------------------------------------
// split xp (with +1 row mapping) into bf16 hi/lo planes
// ---------------------------------------------------------------------------
__global__ __launch_bounds__(256) void split_x(
    const float* __restrict__ x, unsigned short* __restrict__ hi,
    unsigned short* __restrict__ lo)
{
  size_t i = (size_t)blockIdx.x * 256 + threadIdx.x;
  int row = (int)(i >> 6);
  int col = ((int)i & 63) << 3;
  const float* src = x + ((size_t)(row >> 8) * 257 + (row & 255) + 1) * DD + col;
  float4 a = *(const float4*)src;
  float4 b = *(const float4*)(src + 4);
  float v[8] = {a.x, a.y, a.z, a.w, b.x, b.y, b.z, b.w};
  us8 H, L;
#pragma unroll
  for (int j = 0; j < 8; ++j) {
    unsigned short h = f2b(v[j]);
    H[j] = h;
    L[j] = f2b(v[j] - b2f(h));
  }
  size_t o = (size_t)row * DD + col;
  *(us8*)(hi + o) = H;
  *(us8*)(lo + o) = L;
}

// ---------------------------------------------------------------------------
// split + TRANSPOSE a 512x512 weight into bf16 hi/lo planes: out[c][k]=W[k][c]
// ---------------------------------------------------------------------------
__global__ __launch_bounds__(256) void split_w(
    const float* __restrict__ W, unsigned short* __restrict__ hiT,
    unsigned short* __restrict__ loT)
{
  __shared__ float T[64][65];
  const int t = threadIdx.x;
  const int r0 = blockIdx.y * 64, c0 = blockIdx.x * 64;
  const int lr = t >> 2, lc4 = (t & 3) << 4;
#pragma unroll
  for (int j = 0; j < 4; ++j) {
    float4 v = *(const float4*)(W + (size_t)(r0 + lr) * DD + c0 + lc4 + j * 4);
    T[lr][lc4 + j * 4 + 0] = v.x;
    T[lr][lc4 + j * 4 + 1] = v.y;
    T[lr][lc4 + j * 4 + 2] = v.z;
    T[lr][lc4 + j * 4 + 3] = v.w;
  }
  __syncthreads();
  us8 H0, L0, H1, L1;
#pragma unroll
  for (int j = 0; j < 8; ++j) {
    float v0 = T[lc4 + j][lr];
    float v1 = T[lc4 + 8 + j][lr];
    unsigned short h0 = f2b(v0), h1 = f2b(v1);
    H0[j] = h0; L0[j] = f2b(v0 - b2f(h0));
    H1[j] = h1; L1[j] = f2b(v1 - b2f(h1));
  }
  size_t o = (size_t)(c0 + lr) * DD + r0 + lc4;
  *(us8*)(hiT + o) = H0;
  *(us8*)(hiT + o + 8) = H1;
  *(us8*)(loT + o) = L0;
  *(us8*)(loT + o + 8) = L1;
}

// ---------------------------------------------------------------------------
// bf16x3 split MFMA GEMM, now 2-PHASE DOUBLE-BUFFERED (T3 minimum recipe):
// issue next K-tile's global_load_lds BEFORE ds_read+MFMA of current tile;
// single barrier per K-step. MFMA chain order unchanged -> bit-identical
// output to the R2/R3 gemm3. XCD swizzle for A/B panel L2 reuse.
// ---------------------------------------------------------------------------
__global__ __launch_bounds__(256) void gemm3(
    const unsigned short* __restrict__ Ahi, const unsigned short* __restrict__ Alo,
    const unsigned short* __restrict__ BhiT, const unsigned short* __restrict__ BloT,
    const float* __restrict__ bias, float* __restrict__ C)
{
  constexpr int PLANE = 4096;                    // ushorts per 128x32 tile
  __shared__ unsigned short lds[2 * 4 * PLANE];  // 64 KiB: [buf][Ah,Al,Bh,Bl]
  const int tid = threadIdx.x;
  const int wave = tid >> 6, lane = tid & 63;
  const int wr = wave >> 1, wc = wave & 1;

  // bijective XCD swizzle: 512 blocks, 64 per XCD
  const int lid = blockIdx.x + (blockIdx.y << 2);      // gridDim.x == 4
  const int swz = (lid & 7) * 64 + (lid >> 3);
  const int row0 = (swz >> 2) * 128, col0 = (swz & 3) * 128;

  const int lr = lane & 15, lk = lane >> 4;
  f32x4 acc[4][4] = {};

  const int sr = tid >> 2;
  const int schunk = (tid & 3) ^ ((sr >> 1) & 3);      // pre-swizzled source
  const unsigned int wb = (unsigned int)wave * 512;    // wave-uniform LDS base
  const size_t ga0 = (size_t)(row0 + sr) * DD + (schunk << 3);
  const size_t ga1 = ga0 + (size_t)64 * DD;
  const size_t gb0 = (size_t)(col0 + sr) * DD + (schunk << 3);
  const size_t gb1 = gb0 + (size_t)64 * DD;

  int aoff[4], boff[4];
#pragma unroll
  for (int m = 0; m < 4; ++m) {
    int row = wr * 64 + m * 16 + lr;
    aoff[m] = row * 32 + ((lk ^ ((row >> 1) & 3)) << 3);
  }
#pragma unroll
  for (int n = 0; n < 4; ++n) {
    int row = wc * 64 + n * 16 + lr;
    boff[n] = row * 32 + ((lk ^ ((row >> 1) & 3)) << 3);
  }

#define G3_STAGE(buf, k0)                                          \
  { unsigned short* L = lds + (buf) * (4 * PLANE);                 \
    gload16(Ahi  + ga0 + (k0), L + wb);                            \
    gload16(Ahi  + ga1 + (k0), L + wb + 2048);                     \
    gload16(Alo  + ga0 + (k0), L + PLANE + wb);                    \
    gload16(Alo  + ga1 + (k0), L + PLANE + wb + 2048);             \
    gload16(BhiT + gb0 + (k0), L + 2 * PLANE + wb);                \
    gload16(BhiT + gb1 + (k0), L + 2 * PLANE + wb + 2048);         \
    gload16(BloT + gb0 + (k0), L + 3 * PLANE + wb);                \
    gload16(BloT + gb1 + (k0), L + 3 * PLANE + wb + 2048); }

  G3_STAGE(0, 0)
  __syncthreads();

  for (int t = 0; t < 16; ++t) {
    const int cur = t & 1;
    if (t < 15) G3_STAGE(cur ^ 1, (t + 1) << 5)      // prefetch in flight

    const unsigned short* L = lds + cur * (4 * PLANE);
    bf16x8 a[8], b[8];
#pragma unroll
    for (int m = 0; m < 4; ++m) {
      a[m]     = *(const bf16x8*)(L + aoff[m]);
      a[m + 4] = *(const bf16x8*)(L + PLANE + aoff[m]);
    }
#pragma unroll
    for (int n = 0; n < 4; ++n) {
      b[n]     = *(const bf16x8*)(L + 2 * PLANE + boff[n]);
      b[n + 4] = *(const bf16x8*)(L + 3 * PLANE + boff[n]);
    }
#pragma unroll
    for (int m = 0; m < 4; ++m)
#pragma unroll
      for (int n = 0; n < 4; ++n) {
        f32x4 c = acc[m][n];
        c = __builtin_amdgcn_mfma_f32_16x16x32_bf16(a[m],     b[n],     c, 0, 0, 0);
        c = __builtin_amdgcn_mfma_f32_16x16x32_bf16(a[m],     b[n + 4], c, 0, 0, 0);
        c = __builtin_amdgcn_mfma_f32_16x16x32_bf16(a[m + 4], b[n],     c, 0, 0, 0);
        acc[m][n] = c;
      }
    __syncthreads();     // drains prefetch (vmcnt) + all reads of cur
  }

  float bcol[4];
#pragma unroll
  for (int n = 0; n < 4; ++n) bcol[n] = bias[col0 + wc * 64 + n * 16 + lr];
#pragma unroll
  for (int m = 0; m < 4; ++m)
#pragma unroll
    for (int j = 0; j < 4; ++j) {
      int r = row0 + wr * 64 + m * 16 + lk * 4 + j;
#pragma unroll
      for (int n = 0; n < 4; ++n)
        C[(size_t)r * DD + col0 + wc * 64 + n * 16 + lr] = acc[m][n][j] + bcol[n];
    }
}

// ---------------------------------------------------------------------------
// l2norm / topk — routing path, unchanged
// ---------------------------------------------------------------------------
__global__ __launch_bounds__(256) void l2norm_rows(float* __restrict__ X)
{
  const int row = blockIdx.x * 4 + (threadIdx.x >> 6);
  const int lane = threadIdx.x & 63;
  float* base = X + (long)row * DD + lane * 8;
  float4 u = *(float4*)base;
  float4 w = *(float4*)(base + 4);
  float s = u.x * u.x + u.y * u.y + u.z * u.z + u.w * u.w +
            w.x * w.x + w.y * w.y + w.z * w.z + w.w * w.w;
#pragma unroll
  for (int off = 1; off < 64; off <<= 1) s += __shfl_xor(s, off);
  float inv = 1.0f / sqrtf(s + 1e-12f);
  u.x *= inv; u.y *= inv; u.z *= inv; u.w *= inv;
  w.x *= inv; w.y *= inv; w.z *= inv; w.w *= inv;
  *(float4*)base = u;
  *(float4*)(base + 4) = w;
}

__global__ __launch_bounds__(256) void topk_routes(
    const float* __restrict__ S, const float* __restrict__ pb,
    int* __restrict__ routes)
{
  const int row = blockIdx.x * 4 + (threadIdx.x >> 6);
  const int lane = threadIdx.x & 63;
  const int p = row & 255;
  const float* srow = S + (long)row * 256;
  float v[4];
  int id[4];
#pragma unroll
  for (int i = 0; i < 4; ++i) {
    int q = i * 64 + lane;
    float s = srow[q] + pb[p * 256 + q];
    if (q == p) s = -1e9f;
    v[i] = s;
    id[i] = q;
  }
  for (int t = 0; t < 8; ++t) {
    float bv = v[0]; int bi = id[0]; int bs = 0;
#pragma unroll
    for (int i = 1; i < 4; ++i)
      if (v[i] > bv || (v[i] == bv && id[i] < bi)) { bv = v[i]; bi = id[i]; bs = i; }
    float rv = bv; int ri = bi;
#pragma unroll
    for (int off = 1; off < 64; off <<= 1) {
      float ov = __shfl_xor(rv, off);
      int oi = __shfl_xor(ri, off);
      if (ov > rv || (ov == rv && oi < ri)) { rv = ov; ri = oi; }
    }
    if (bi == ri) v[bs] = -INFINITY;
    if (lane == 0) routes[row * 8 + t] = ri;
  }
}

// ---------------------------------------------------------------------------
// Gathered 8-key attention; emits ctx as bf16 hi/lo planes for gemm3.
// ---------------------------------------------------------------------------
__global__ __launch_bounds__(512) void wormhole_attn(
    const float* __restrict__ qh, const float* __restrict__ kh,
    const float* __restrict__ vh, const int* __restrict__ routes,
    unsigned short* __restrict__ chi, unsigned short* __restrict__ clo)
{
  const int bp = blockIdx.x;
  const int b = bp >> 8;
  const int tid = threadIdx.x;
  __shared__ int rs[8];
  if (tid < 8) rs[tid] = routes[bp * 8 + tid];
  __syncthreads();

  const float q = qh[(long)bp * DD + tid];
  long rbase[8];
  float s[8];
#pragma unroll
  for (int k = 0; k < 8; ++k) {
    long roff = ((long)((b << 8) | rs[k])) * DD + tid;
    rbase[k] = roff;
    float t = q * kh[roff];
#pragma unroll
    for (int off = 1; off < 64; off <<= 1) t += __shfl_xor(t, off);
    s[k] = t * 0.125f;
  }
  float m = s[0];
#pragma unroll
  for (int k = 1; k < 8; ++k) m = fmaxf(m, s[k]);
  float e[8], sum = 0.f;
#pragma unroll
  for (int k = 0; k < 8; ++k) { e[k] = expf(s[k] - m); sum += e[k]; }
  float inv = 1.0f / sum;
  float c = 0.f;
#pragma unroll
  for (int k = 0; k < 8; ++k) c = fmaf(e[k] * inv, vh[rbase[k]], c);
  unsigned short h = f2b(c);
  chi[(size_t)bp * DD + tid] = h;
  clo[(size_t)bp * DD + tid] = f2b(c - b2f(h));
}

// ---------------------------------------------------------------------------
extern "C" void kernel_launch(void* const* d_in, const int* in_sizes, int n_in,
                              void* d_out, int out_size, void* d_ws, size_t ws_size,
                              hipStream_t stream)
{
  const float* x        = (const float*)d_in[0];
  const float* wq_r     = (const float*)d_in[1];
  const float* bq_r     = (const float*)d_in[2];
  const float* wk_r     = (const float*)d_in[3];
  const float* bk_r     = (const float*)d_in[4];
  const float* pos_bias = (const float*)d_in[5];
  const float* wq       = (const float*)d_in[6];
  const float* bq       = (const float*)d_in[7];
  const float* wk       = (const float*)d_in[8];
  const float* bk       = (const float*)d_in[9];
  const float* wv       = (const float*)d_in[10];
  const float* bv       = (const float*)d_in[11];
  const float* wo       = (const float*)d_in[12];
  const float* bo       = (const float*)d_in[13];

  char* w = (char*)d_ws;
  const size_t SLOT = (size_t)MROWS * DD * sizeof(float);   // 33.55 MB
  unsigned short* Xhi = (unsigned short*)w;
  unsigned short* Xlo = (unsigned short*)(w + SLOT / 2);
  float* S0 = (float*)(w + SLOT);
  float* S1 = (float*)(w + 2 * SLOT);
  float* S2 = (float*)(w + 3 * SLOT);
  int* routes = (int*)(w + 4 * SLOT);
  const size_t WSZ = (size_t)DD * DD * sizeof(unsigned short);
  unsigned short* Wp = (unsigned short*)(w + 4 * SLOT + (1 << 20));
  unsigned short* Wq_hi = Wp + 0 * (WSZ / 2), *Wq_lo = Wp + 1 * (WSZ / 2);
  unsigned short* Wk_hi = Wp + 2 * (WSZ / 2), *Wk_lo = Wp + 3 * (WSZ / 2);
  unsigned short* Wv_hi = Wp + 4 * (WSZ / 2), *Wv_lo = Wp + 5 * (WSZ / 2);
  unsigned short* Wo_hi = Wp + 6 * (WSZ / 2), *Wo_lo = Wp + 7 * (WSZ / 2);

  unsigned short* Chi = Xhi;   // ctx reuses X region (X dead after vh GEMM)
  unsigned short* Clo = Xlo;

  dim3 blk(256);
  dim3 g3(4, 128);              // gemm3: N/128 x M/128
  dim3 gw(8, 8);
  dim3 gr(8, 128);              // merged routing: 2N/128 x M/128
  dim3 gs(4, 4, 64);            // scores: 64x64 tiles x batch

  // --- operand prep (bf16 hi/lo splits)
  split_x<<<4096, 256, 0, stream>>>(x, Xhi, Xlo);
  split_w<<<gw, 256, 0, stream>>>(wq, Wq_hi, Wq_lo);
  split_w<<<gw, 256, 0, stream>>>(wk, Wk_hi, Wk_lo);
  split_w<<<gw, 256, 0, stream>>>(wv, Wv_hi, Wv_lo);
  split_w<<<gw, 256, 0, stream>>>(wo, Wo_hi, Wo_lo);

  // --- routing path (f32; merged q_r/k_r dispatch, bit-identical fma order)
  gemm_routing<<<gr, blk, 0, stream>>>(x, wq_r, bq_r, wk_r, bk_r, S0, S1);
  l2norm_rows<<<MROWS / 4, 256, 0, stream>>>(S0);
  l2norm_rows<<<MROWS / 4, 256, 0, stream>>>(S1);
  gemm_scores<<<gs, blk, 0, stream>>>(S0, S1, S2);
  topk_routes<<<MROWS / 4, 256, 0, stream>>>(S2, pos_bias, routes);

  // --- head projections via bf16x3 MFMA (2-phase dbuf)
  gemm3<<<g3, blk, 0, stream>>>(Xhi, Xlo, Wq_hi, Wq_lo, bq, S0);
  gemm3<<<g3, blk, 0, stream>>>(Xhi, Xlo, Wk_hi, Wk_lo, bk, S1);
  gemm3<<<g3, blk, 0, stream>>>(Xhi, Xlo, Wv_hi, Wv_lo, bv, S2);

  // --- gathered attention (emits ctx hi/lo) + output projection (MFMA)
  wormhole_attn<<<MROWS, 512, 0, stream>>>(S0, S1, S2, routes, Chi, Clo);
  gemm3<<<g3, blk, 0, stream>>>(Chi, Clo, Wo_hi, Wo_lo, bo, (float*)d_out);
}

// Round 6
// 642.746 us; speedup vs baseline: 1.0170x; 1.0170x over previous
//
#include <hip/hip_runtime.h>
#include <math.h>

constexpr int PB = 256;          // positions per batch
constexpr int DD = 512;          // model dim
constexpr int NB = 64;           // batch
constexpr int MROWS = NB * PB;   // 16384 rows

typedef __bf16 bf16x8 __attribute__((ext_vector_type(8)));
typedef float f32x4 __attribute__((ext_vector_type(4)));
typedef unsigned short us8 __attribute__((ext_vector_type(8)));

__device__ __forceinline__ unsigned short f2b(float f) {
  unsigned int u = __float_as_uint(f);
  u += 0x7FFFu + ((u >> 16) & 1u);        // round-to-nearest-even
  return (unsigned short)(u >> 16);
}
__device__ __forceinline__ float b2f(unsigned short h) {
  return __uint_as_float(((unsigned int)h) << 16);
}

// direct global->LDS DMA, 16B per lane; lds dest must be wave-uniform base
__device__ __forceinline__ void gload16(const void* g, const void* l) {
  __builtin_amdgcn_global_load_lds(
      (const __attribute__((address_space(1))) unsigned int*)(uintptr_t)g,
      (__attribute__((address_space(3))) unsigned int*)(unsigned int)(uintptr_t)l,
      16, 0, 0);
}

// ---------------------------------------------------------------------------
// MERGED f32 routing GEMM (unchanged from R4 — best measured: 205 us both).
// ---------------------------------------------------------------------------
__global__ __launch_bounds__(256) void gemm_routing(
    const float* __restrict__ x,
    const float* __restrict__ wq_r, const float* __restrict__ bq_r,
    const float* __restrict__ wk_r, const float* __restrict__ bk_r,
    float* __restrict__ S0, float* __restrict__ S1)
{
  __shared__ float As[2][16][132];
  __shared__ float Bs[2][16][132];
  const int tid = threadIdx.x;
  const int tx = tid & 15, ty = tid >> 4;

  const int lid = blockIdx.x + (blockIdx.y << 3);     // gridDim.x == 8
  const int swz = (lid & 7) * 128 + (lid >> 3);
  const int bx = swz & 7, by = swz >> 3;
  const float* Wm   = (bx < 4) ? wq_r : wk_r;
  const float* bias = (bx < 4) ? bq_r : bk_r;
  float* C          = (bx < 4) ? S0 : S1;
  const int row0 = by * 128, col0 = (bx & 3) * 128;

  const int a_r = tid >> 2, a_k4 = (tid & 3) << 2;
  const int g0 = row0 + a_r, g1 = g0 + 64;
  const size_t ag0 = ((size_t)(g0 >> 8) * 257 + (g0 & 255) + 1) * DD + a_k4;
  const size_t ag1 = ((size_t)(g1 >> 8) * 257 + (g1 & 255) + 1) * DD + a_k4;
  const int b_kr = tid >> 5, b_c4 = (tid & 31) << 2;
  const size_t bg0 = (size_t)b_kr * DD + col0 + b_c4;
  const size_t bg1 = bg0 + (size_t)8 * DD;

  float acc[8][8] = {};

  float4 pa0 = *(const float4*)(x + ag0);
  float4 pa1 = *(const float4*)(x + ag1);
  float4 pb0 = *(const float4*)(Wm + bg0);
  float4 pb1 = *(const float4*)(Wm + bg1);

  for (int t = 0; t < 32; ++t) {
    const int buf = t & 1;
    As[buf][a_k4 + 0][a_r] = pa0.x;
    As[buf][a_k4 + 1][a_r] = pa0.y;
    As[buf][a_k4 + 2][a_r] = pa0.z;
    As[buf][a_k4 + 3][a_r] = pa0.w;
    As[buf][a_k4 + 0][a_r + 64] = pa1.x;
    As[buf][a_k4 + 1][a_r + 64] = pa1.y;
    As[buf][a_k4 + 2][a_r + 64] = pa1.z;
    As[buf][a_k4 + 3][a_r + 64] = pa1.w;
    *(float4*)&Bs[buf][b_kr][b_c4] = pb0;
    *(float4*)&Bs[buf][b_kr + 8][b_c4] = pb1;
    __syncthreads();

    if (t < 31) {
      const int k0 = (t + 1) << 4;
      pa0 = *(const float4*)(x + ag0 + k0);
      pa1 = *(const float4*)(x + ag1 + k0);
      pb0 = *(const float4*)(Wm + bg0 + (size_t)k0 * DD);
      pb1 = *(const float4*)(Wm + bg1 + (size_t)k0 * DD);
    }

#pragma unroll
    for (int kk = 0; kk < 16; ++kk) {
      float4 x0 = *(const float4*)&As[buf][kk][ty * 4];
      float4 x1 = *(const float4*)&As[buf][kk][ty * 4 + 64];
      float4 y0 = *(const float4*)&Bs[buf][kk][tx * 4];
      float4 y1 = *(const float4*)&Bs[buf][kk][tx * 4 + 64];
      float av[8] = {x0.x, x0.y, x0.z, x0.w, x1.x, x1.y, x1.z, x1.w};
      float bv[8] = {y0.x, y0.y, y0.z, y0.w, y1.x, y1.y, y1.z, y1.w};
#pragma unroll
      for (int i = 0; i < 8; ++i)
#pragma unroll
        for (int j = 0; j < 8; ++j)
          acc[i][j] = fmaf(av[i], bv[j], acc[i][j]);
    }
  }

#pragma unroll
  for (int ib = 0; ib < 2; ++ib)
#pragma unroll
    for (int i = 0; i < 4; ++i) {
      const int r = row0 + ib * 64 + ty * 4 + i;
#pragma unroll
      for (int jb = 0; jb < 2; ++jb) {
        const int c = col0 + jb * 64 + tx * 4;
        float4 o;
        o.x = acc[ib * 4 + i][jb * 4 + 0] + bias[c + 0];
        o.y = acc[ib * 4 + i][jb * 4 + 1] + bias[c + 1];
        o.z = acc[ib * 4 + i][jb * 4 + 2] + bias[c + 2];
        o.w = acc[ib * 4 + i][jb * 4 + 3] + bias[c + 3];
        *(float4*)(C + (size_t)r * DD + c) = o;
      }
    }
}

// ---------------------------------------------------------------------------
// Batched scores GEMM (f32, 64x64 tiles, 1024 blocks) — R2-proven
// ---------------------------------------------------------------------------
__global__ __launch_bounds__(256) void gemm_scores(
    const float* __restrict__ Q, const float* __restrict__ Kr,
    float* __restrict__ S)
{
  __shared__ float As[16][65];
  __shared__ float Bs[16][65];
  const int b = blockIdx.z;
  const int tid = threadIdx.x;
  const int tx = tid & 15, ty = tid >> 4;
  const int p0 = blockIdx.y * 64, q0 = blockIdx.x * 64;
  const float* Qb = Q + (long)b * PB * DD;
  const float* Kb = Kr + (long)b * PB * DD;
  const int a_r = tid >> 2, a_k = (tid & 3) << 2;
  const int b_n = tid & 63, b_k4 = (tid >> 6) << 2;
  float acc[4][4] = {};

  for (int k0 = 0; k0 < DD; k0 += 16) {
    float4 av = *(const float4*)(Qb + (long)(p0 + a_r) * DD + k0 + a_k);
    As[a_k + 0][a_r] = av.x;
    As[a_k + 1][a_r] = av.y;
    As[a_k + 2][a_r] = av.z;
    As[a_k + 3][a_r] = av.w;
    float4 bv = *(const float4*)(Kb + (long)(q0 + b_n) * DD + k0 + b_k4);
    Bs[b_k4 + 0][b_n] = bv.x;
    Bs[b_k4 + 1][b_n] = bv.y;
    Bs[b_k4 + 2][b_n] = bv.z;
    Bs[b_k4 + 3][b_n] = bv.w;
    __syncthreads();
#pragma unroll
    for (int kk = 0; kk < 16; ++kk) {
      float a[4], b2[4];
#pragma unroll
      for (int i = 0; i < 4; ++i) a[i] = As[kk][ty * 4 + i];
#pragma unroll
      for (int j = 0; j < 4; ++j) b2[j] = Bs[kk][tx * 4 + j];
#pragma unroll
      for (int i = 0; i < 4; ++i)
#pragma unroll
        for (int j = 0; j < 4; ++j)
          acc[i][j] = fmaf(a[i], b2[j], acc[i][j]);
    }
    __syncthreads();
  }

  float* Sb = S + (long)b * PB * PB;
#pragma unroll
  for (int i = 0; i < 4; ++i) {
    int p = p0 + ty * 4 + i;
    int q = q0 + tx * 4;
    float4 o = make_float4(acc[i][0], acc[i][1], acc[i][2], acc[i][3]);
    *(float4*)(Sb + (long)p * PB + q) = o;
  }
}

// ---------------------------------------------------------------------------
// split xp (with +1 row mapping) into bf16 hi/lo planes
// ---------------------------------------------------------------------------
__global__ __launch_bounds__(256) void split_x(
    const float* __restrict__ x, unsigned short* __restrict__ hi,
    unsigned short* __restrict__ lo)
{
  size_t i = (size_t)blockIdx.x * 256 + threadIdx.x;
  int row = (int)(i >> 6);
  int col = ((int)i & 63) << 3;
  const float* src = x + ((size_t)(row >> 8) * 257 + (row & 255) + 1) * DD + col;
  float4 a = *(const float4*)src;
  float4 b = *(const float4*)(src + 4);
  float v[8] = {a.x, a.y, a.z, a.w, b.x, b.y, b.z, b.w};
  us8 H, L;
#pragma unroll
  for (int j = 0; j < 8; ++j) {
    unsigned short h = f2b(v[j]);
    H[j] = h;
    L[j] = f2b(v[j] - b2f(h));
  }
  size_t o = (size_t)row * DD + col;
  *(us8*)(hi + o) = H;
  *(us8*)(lo + o) = L;
}

// ---------------------------------------------------------------------------
// split + TRANSPOSE a 512x512 weight into bf16 hi/lo planes: out[c][k]=W[k][c]
// ---------------------------------------------------------------------------
__global__ __launch_bounds__(256) void split_w(
    const float* __restrict__ W, unsigned short* __restrict__ hiT,
    unsigned short* __restrict__ loT)
{
  __shared__ float T[64][65];
  const int t = threadIdx.x;
  const int r0 = blockIdx.y * 64, c0 = blockIdx.x * 64;
  const int lr = t >> 2, lc4 = (t & 3) << 4;
#pragma unroll
  for (int j = 0; j < 4; ++j) {
    float4 v = *(const float4*)(W + (size_t)(r0 + lr) * DD + c0 + lc4 + j * 4);
    T[lr][lc4 + j * 4 + 0] = v.x;
    T[lr][lc4 + j * 4 + 1] = v.y;
    T[lr][lc4 + j * 4 + 2] = v.z;
    T[lr][lc4 + j * 4 + 3] = v.w;
  }
  __syncthreads();
  us8 H0, L0, H1, L1;
#pragma unroll
  for (int j = 0; j < 8; ++j) {
    float v0 = T[lc4 + j][lr];
    float v1 = T[lc4 + 8 + j][lr];
    unsigned short h0 = f2b(v0), h1 = f2b(v1);
    H0[j] = h0; L0[j] = f2b(v0 - b2f(h0));
    H1[j] = h1; L1[j] = f2b(v1 - b2f(h1));
  }
  size_t o = (size_t)(c0 + lr) * DD + r0 + lc4;
  *(us8*)(hiT + o) = H0;
  *(us8*)(hiT + o + 8) = H1;
  *(us8*)(loT + o) = L0;
  *(us8*)(loT + o + 8) = L1;
}

// ---------------------------------------------------------------------------
// bf16x3 split MFMA GEMM, MULTI-WEIGHT: one dispatch computes NW projections
// of the same A (shared L2 panels, bigger grid -> fills the VGPR-limited
// 3 blocks/CU). Body = R2-proven single-buffer structure (32 KiB LDS).
// MFMA chain per output unchanged -> bit-identical to R2/R3 outputs.
// Grid: (4*NW, 128); bijective XCD swizzle over 512*NW blocks.
// ---------------------------------------------------------------------------
template<int NW>
__global__ __launch_bounds__(256) void gemm3m(
    const unsigned short* __restrict__ Ahi, const unsigned short* __restrict__ Alo,
    const unsigned short* __restrict__ B0h, const unsigned short* __restrict__ B0l,
    const unsigned short* __restrict__ B1h, const unsigned short* __restrict__ B1l,
    const unsigned short* __restrict__ B2h, const unsigned short* __restrict__ B2l,
    const float* __restrict__ bias0, const float* __restrict__ bias1,
    const float* __restrict__ bias2,
    float* __restrict__ C0, float* __restrict__ C1, float* __restrict__ C2)
{
  __shared__ unsigned short Ah[128 * 32], Al[128 * 32];
  __shared__ unsigned short Bh[128 * 32], Bl[128 * 32];
  const int tid = threadIdx.x;
  const int wave = tid >> 6, lane = tid & 63;
  const int wr = wave >> 1, wc = wave & 1;

  // bijective XCD swizzle: nwg = 512*NW (multiple of 8), chunk = 64*NW
  const int lid = blockIdx.y * (4 * NW) + blockIdx.x;
  const int swz = (lid & 7) * (64 * NW) + (lid >> 3);
  const int wsel = swz >> 9;                 // 0..NW-1
  const int r9 = swz & 511;
  const int row0 = (r9 >> 2) * 128, col0 = (r9 & 3) * 128;

  const unsigned short* BhiT = (NW == 1 || wsel == 0) ? B0h : (wsel == 1) ? B1h : B2h;
  const unsigned short* BloT = (NW == 1 || wsel == 0) ? B0l : (wsel == 1) ? B1l : B2l;
  const float* bias          = (NW == 1 || wsel == 0) ? bias0 : (wsel == 1) ? bias1 : bias2;
  float* C                   = (NW == 1 || wsel == 0) ? C0 : (wsel == 1) ? C1 : C2;

  const int lr = lane & 15, lk = lane >> 4;
  f32x4 acc[4][4] = {};

  const int sr = tid >> 2;
  const int schunk = (tid & 3) ^ ((sr >> 1) & 3);      // pre-swizzled source
  const unsigned int lds0 = (unsigned int)wave * 512;  // ushort units
  const size_t ga0 = (size_t)(row0 + sr) * DD + (schunk << 3);
  const size_t ga1 = ga0 + (size_t)64 * DD;
  const size_t gb0 = (size_t)(col0 + sr) * DD + (schunk << 3);
  const size_t gb1 = gb0 + (size_t)64 * DD;

  int aoff[4], boff[4];
#pragma unroll
  for (int m = 0; m < 4; ++m) {
    int row = wr * 64 + m * 16 + lr;
    aoff[m] = row * 32 + ((lk ^ ((row >> 1) & 3)) << 3);
  }
#pragma unroll
  for (int n = 0; n < 4; ++n) {
    int row = wc * 64 + n * 16 + lr;
    boff[n] = row * 32 + ((lk ^ ((row >> 1) & 3)) << 3);
  }

  for (int k0 = 0; k0 < DD; k0 += 32) {
    gload16(Ahi + ga0 + k0, Ah + lds0);
    gload16(Ahi + ga1 + k0, Ah + lds0 + 2048);
    gload16(Alo + ga0 + k0, Al + lds0);
    gload16(Alo + ga1 + k0, Al + lds0 + 2048);
    gload16(BhiT + gb0 + k0, Bh + lds0);
    gload16(BhiT + gb1 + k0, Bh + lds0 + 2048);
    gload16(BloT + gb0 + k0, Bl + lds0);
    gload16(BloT + gb1 + k0, Bl + lds0 + 2048);
    __syncthreads();

    bf16x8 a[8], b[8];
#pragma unroll
    for (int m = 0; m < 4; ++m) {
      a[m]     = *(const bf16x8*)(Ah + aoff[m]);
      a[m + 4] = *(const bf16x8*)(Al + aoff[m]);
    }
#pragma unroll
    for (int n = 0; n < 4; ++n) {
      b[n]     = *(const bf16x8*)(Bh + boff[n]);
      b[n + 4] = *(const bf16x8*)(Bl + boff[n]);
    }
#pragma unroll
    for (int m = 0; m < 4; ++m)
#pragma unroll
      for (int n = 0; n < 4; ++n) {
        f32x4 c = acc[m][n];
        c = __builtin_amdgcn_mfma_f32_16x16x32_bf16(a[m],     b[n],     c, 0, 0, 0);
        c = __builtin_amdgcn_mfma_f32_16x16x32_bf16(a[m],     b[n + 4], c, 0, 0, 0);
        c = __builtin_amdgcn_mfma_f32_16x16x32_bf16(a[m + 4], b[n],     c, 0, 0, 0);
        acc[m][n] = c;
      }
    __syncthreads();
  }

  float bcol[4];
#pragma unroll
  for (int n = 0; n < 4; ++n) bcol[n] = bias[col0 + wc * 64 + n * 16 + lr];
#pragma unroll
  for (int m = 0; m < 4; ++m)
#pragma unroll
    for (int j = 0; j < 4; ++j) {
      int r = row0 + wr * 64 + m * 16 + lk * 4 + j;
#pragma unroll
      for (int n = 0; n < 4; ++n)
        C[(size_t)r * DD + col0 + wc * 64 + n * 16 + lr] = acc[m][n][j] + bcol[n];
    }
}

// ---------------------------------------------------------------------------
// l2norm (one dispatch over the contiguous S0|S1 region) / topk
// ---------------------------------------------------------------------------
__global__ __launch_bounds__(256) void l2norm_rows(float* __restrict__ X)
{
  const int row = blockIdx.x * 4 + (threadIdx.x >> 6);
  const int lane = threadIdx.x & 63;
  float* base = X + (long)row * DD + lane * 8;
  float4 u = *(float4*)base;
  float4 w = *(float4*)(base + 4);
  float s = u.x * u.x + u.y * u.y + u.z * u.z + u.w * u.w +
            w.x * w.x + w.y * w.y + w.z * w.z + w.w * w.w;
#pragma unroll
  for (int off = 1; off < 64; off <<= 1) s += __shfl_xor(s, off);
  float inv = 1.0f / sqrtf(s + 1e-12f);
  u.x *= inv; u.y *= inv; u.z *= inv; u.w *= inv;
  w.x *= inv; w.y *= inv; w.z *= inv; w.w *= inv;
  *(float4*)base = u;
  *(float4*)(base + 4) = w;
}

__global__ __launch_bounds__(256) void topk_routes(
    const float* __restrict__ S, const float* __restrict__ pb,
    int* __restrict__ routes)
{
  const int row = blockIdx.x * 4 + (threadIdx.x >> 6);
  const int lane = threadIdx.x & 63;
  const int p = row & 255;
  const float* srow = S + (long)row * 256;
  float v[4];
  int id[4];
#pragma unroll
  for (int i = 0; i < 4; ++i) {
    int q = i * 64 + lane;
    float s = srow[q] + pb[p * 256 + q];
    if (q == p) s = -1e9f;
    v[i] = s;
    id[i] = q;
  }
  for (int t = 0; t < 8; ++t) {
    float bv = v[0]; int bi = id[0]; int bs = 0;
#pragma unroll
    for (int i = 1; i < 4; ++i)
      if (v[i] > bv || (v[i] == bv && id[i] < bi)) { bv = v[i]; bi = id[i]; bs = i; }
    float rv = bv; int ri = bi;
#pragma unroll
    for (int off = 1; off < 64; off <<= 1) {
      float ov = __shfl_xor(rv, off);
      int oi = __shfl_xor(ri, off);
      if (ov > rv || (ov == rv && oi < ri)) { rv = ov; ri = oi; }
    }
    if (bi == ri) v[bs] = -INFINITY;
    if (lane == 0) routes[row * 8 + t] = ri;
  }
}

// ---------------------------------------------------------------------------
// Gathered 8-key attention; emits ctx as bf16 hi/lo planes for gemm3m.
// ---------------------------------------------------------------------------
__global__ __launch_bounds__(512) void wormhole_attn(
    const float* __restrict__ qh, const float* __restrict__ kh,
    const float* __restrict__ vh, const int* __restrict__ routes,
    unsigned short* __restrict__ chi, unsigned short* __restrict__ clo)
{
  const int bp = blockIdx.x;
  const int b = bp >> 8;
  const int tid = threadIdx.x;
  __shared__ int rs[8];
  if (tid < 8) rs[tid] = routes[bp * 8 + tid];
  __syncthreads();

  const float q = qh[(long)bp * DD + tid];
  long rbase[8];
  float s[8];
#pragma unroll
  for (int k = 0; k < 8; ++k) {
    long roff = ((long)((b << 8) | rs[k])) * DD + tid;
    rbase[k] = roff;
    float t = q * kh[roff];
#pragma unroll
    for (int off = 1; off < 64; off <<= 1) t += __shfl_xor(t, off);
    s[k] = t * 0.125f;
  }
  float m = s[0];
#pragma unroll
  for (int k = 1; k < 8; ++k) m = fmaxf(m, s[k]);
  float e[8], sum = 0.f;
#pragma unroll
  for (int k = 0; k < 8; ++k) { e[k] = expf(s[k] - m); sum += e[k]; }
  float inv = 1.0f / sum;
  float c = 0.f;
#pragma unroll
  for (int k = 0; k < 8; ++k) c = fmaf(e[k] * inv, vh[rbase[k]], c);
  unsigned short h = f2b(c);
  chi[(size_t)bp * DD + tid] = h;
  clo[(size_t)bp * DD + tid] = f2b(c - b2f(h));
}

// ---------------------------------------------------------------------------
extern "C" void kernel_launch(void* const* d_in, const int* in_sizes, int n_in,
                              void* d_out, int out_size, void* d_ws, size_t ws_size,
                              hipStream_t stream)
{
  const float* x        = (const float*)d_in[0];
  const float* wq_r     = (const float*)d_in[1];
  const float* bq_r     = (const float*)d_in[2];
  const float* wk_r     = (const float*)d_in[3];
  const float* bk_r     = (const float*)d_in[4];
  const float* pos_bias = (const float*)d_in[5];
  const float* wq       = (const float*)d_in[6];
  const float* bq       = (const float*)d_in[7];
  const float* wk       = (const float*)d_in[8];
  const float* bk       = (const float*)d_in[9];
  const float* wv       = (const float*)d_in[10];
  const float* bv       = (const float*)d_in[11];
  const float* wo       = (const float*)d_in[12];
  const float* bo       = (const float*)d_in[13];

  char* w = (char*)d_ws;
  const size_t SLOT = (size_t)MROWS * DD * sizeof(float);   // 33.55 MB
  unsigned short* Xhi = (unsigned short*)w;
  unsigned short* Xlo = (unsigned short*)(w + SLOT / 2);
  float* S0 = (float*)(w + SLOT);
  float* S1 = (float*)(w + 2 * SLOT);
  float* S2 = (float*)(w + 3 * SLOT);
  int* routes = (int*)(w + 4 * SLOT);
  const size_t WSZ = (size_t)DD * DD * sizeof(unsigned short);
  unsigned short* Wp = (unsigned short*)(w + 4 * SLOT + (1 << 20));
  unsigned short* Wq_hi = Wp + 0 * (WSZ / 2), *Wq_lo = Wp + 1 * (WSZ / 2);
  unsigned short* Wk_hi = Wp + 2 * (WSZ / 2), *Wk_lo = Wp + 3 * (WSZ / 2);
  unsigned short* Wv_hi = Wp + 4 * (WSZ / 2), *Wv_lo = Wp + 5 * (WSZ / 2);
  unsigned short* Wo_hi = Wp + 6 * (WSZ / 2), *Wo_lo = Wp + 7 * (WSZ / 2);

  unsigned short* Chi = Xhi;   // ctx reuses X region (X dead after vh GEMM)
  unsigned short* Clo = Xlo;

  dim3 blk(256);
  dim3 gw(8, 8);
  dim3 gr(8, 128);              // merged routing
  dim3 gs(4, 4, 64);            // scores: 64x64 tiles x batch
  dim3 g3a(12, 128);            // gemm3m<3>: 1536 blocks
  dim3 g3b(4, 128);             // gemm3m<1>: 512 blocks

  // --- operand prep (bf16 hi/lo splits)
  split_x<<<4096, 256, 0, stream>>>(x, Xhi, Xlo);
  split_w<<<gw, 256, 0, stream>>>(wq, Wq_hi, Wq_lo);
  split_w<<<gw, 256, 0, stream>>>(wk, Wk_hi, Wk_lo);
  split_w<<<gw, 256, 0, stream>>>(wv, Wv_hi, Wv_lo);
  split_w<<<gw, 256, 0, stream>>>(wo, Wo_hi, Wo_lo);

  // --- routing path (f32; bit-identical fma order preserved)
  gemm_routing<<<gr, blk, 0, stream>>>(x, wq_r, bq_r, wk_r, bk_r, S0, S1);
  l2norm_rows<<<(2 * MROWS) / 4, 256, 0, stream>>>(S0);   // S0|S1 contiguous
  gemm_scores<<<gs, blk, 0, stream>>>(S0, S1, S2);
  topk_routes<<<MROWS / 4, 256, 0, stream>>>(S2, pos_bias, routes);

  // --- q,k,v head projections fused into ONE bf16x3 MFMA dispatch
  gemm3m<3><<<g3a, blk, 0, stream>>>(Xhi, Xlo,
      Wq_hi, Wq_lo, Wk_hi, Wk_lo, Wv_hi, Wv_lo,
      bq, bk, bv, S0, S1, S2);

  // --- gathered attention (emits ctx hi/lo) + output projection (MFMA)
  wormhole_attn<<<MROWS, 512, 0, stream>>>(S0, S1, S2, routes, Chi, Clo);
  gemm3m<1><<<g3b, blk, 0, stream>>>(Chi, Clo,
      Wo_hi, Wo_lo, Wo_hi, Wo_lo, Wo_hi, Wo_lo,
      bo, bo, bo, (float*)d_out, (float*)d_out, (float*)d_out);
}